// Round 7
// baseline (429.927 us; speedup 1.0000x reference)
//
#include <hip/hip_runtime.h>
#include <stdint.h>

// BartAttention fused: out = ((f*exp(QK^T))/rowsum) @ V heads -> @ Wo + bo
// B=2 T=2048 D=1024 H=16 hd=64. Inputs fp32, output fp32, intermediates bf16.
// R7: attn f-prefetch pipeline (reg dbuf); q/k in [B,T,D]; v-store via LDS
// transpose epilogue (coalesced 256B rows).

typedef __attribute__((ext_vector_type(8))) short short8;
typedef __attribute__((ext_vector_type(4))) short short4v;
typedef __attribute__((ext_vector_type(4))) float f32x4;
typedef unsigned short u16;

#define T_SEQ 2048
#define NH    16
#define HD    64
#define DM    1024

__device__ __forceinline__ float b2f(u16 h) {
  union { unsigned u; float f; } v; v.u = ((unsigned)h) << 16; return v.f;
}
__device__ __forceinline__ u16 f2bf(float x) {  // round-to-nearest-even
  union { float f; unsigned u; } v; v.f = x;
  unsigned r = v.u + 0x7fffu + ((v.u >> 16) & 1u);
  return (u16)(r >> 16);
}
__device__ __forceinline__ short8 cvt8(const float* p) {
  const f32x4 a = *(const f32x4*)p;
  const f32x4 b = *(const f32x4*)(p + 4);
  short8 o;
  o[0] = (short)f2bf(a[0]); o[1] = (short)f2bf(a[1]);
  o[2] = (short)f2bf(a[2]); o[3] = (short)f2bf(a[3]);
  o[4] = (short)f2bf(b[0]); o[5] = (short)f2bf(b[1]);
  o[6] = (short)f2bf(b[2]); o[7] = (short)f2bf(b[3]);
  return o;
}
__device__ __forceinline__ void gl_lds16(const void* g, void* l) {
  __builtin_amdgcn_global_load_lds(
      (const __attribute__((address_space(1))) void*)g,
      (__attribute__((address_space(3))) void*)l, 16, 0, 0);
}

// ---------------- fp32 -> bf16 prepass ----------------
#define HS_CH 524288u
#define F_CH  1048576u
#define W_CH  131072u
__global__ void cvt_kernel(const float* __restrict__ hs, const float* __restrict__ f,
                           const float* __restrict__ Wq, const float* __restrict__ Wk,
                           const float* __restrict__ Wv, const float* __restrict__ Wo,
                           u16* __restrict__ hsb, u16* __restrict__ fb,
                           u16* __restrict__ Wqb, u16* __restrict__ Wkb,
                           u16* __restrict__ Wvb, u16* __restrict__ Wob) {
  unsigned c = blockIdx.x * 256 + threadIdx.x;
  const float* s; u16* d; unsigned off;
  if (c < HS_CH)                       { s = hs; d = hsb; off = c; }
  else if ((c -= HS_CH) < F_CH)        { s = f;  d = fb;  off = c; }
  else if ((c -= F_CH) < W_CH)         { s = Wq; d = Wqb; off = c; }
  else if ((c -= W_CH) < W_CH)         { s = Wk; d = Wkb; off = c; }
  else if ((c -= W_CH) < W_CH)         { s = Wv; d = Wvb; off = c; }
  else                                 { s = Wo; d = Wob; off = c - W_CH; }
  *(short8*)&d[(size_t)off * 8] = cvt8(&s[(size_t)off * 8]);
}

// ---------------- QKV projection GEMM ----------------
// q,k -> [B,T,D] row-major (m-major); v -> [B,H,hd,T] via LDS-transpose epilogue.
__global__ __launch_bounds__(256, 4) void qkv_kernel(
    const void* __restrict__ Xv,
    const void* __restrict__ Wqv, const float* __restrict__ bq,
    const void* __restrict__ Wkv, const float* __restrict__ bk,
    const void* __restrict__ Wvv, const float* __restrict__ bv,
    int isf32,
    u16* __restrict__ q, u16* __restrict__ k, u16* __restrict__ v)
{
  const int z = blockIdx.z;
  const void* Wp = (z == 0) ? Wqv : (z == 1) ? Wkv : Wvv;
  const float* bias = (z == 0) ? bq : (z == 1) ? bk : bv;

  // smem: staging (16 KB: lsA | lsB) reused by the z=2 epilogue (128x136 u16)
  __shared__ alignas(16) u16 smem[17408];
  u16* lsA = smem;          // [slab][row][8] = [(slab*128+row)*8]
  u16* lsB = smem + 4096;

  const int tid = threadIdx.x;
  const int lane = tid & 63;
  const int wv = tid >> 6;
  const int lq = lane >> 4, li = lane & 15;
  const int wm = wv >> 1, wn = wv & 1;

  const int m0 = blockIdx.y * 128;
  const int n0 = blockIdx.x * 128;

  f32x4 acc[4][4];
#pragma unroll
  for (int i = 0; i < 4; i++)
#pragma unroll
    for (int j = 0; j < 4; j++) acc[i][j] = (f32x4){0.f, 0.f, 0.f, 0.f};

  for (int k0 = 0; k0 < DM; k0 += 32) {
    if (isf32) {
      const float* X32 = (const float*)Xv;
      const float* W32 = (const float*)Wp;
#pragma unroll
      for (int r = 0; r < 2; ++r) {
        const int idx = tid + 256 * r;
        const int row = idx >> 2, slab = idx & 3;
        *(short8*)&lsA[(slab * 128 + row) * 8] = cvt8(&X32[(size_t)(m0 + row) * DM + k0 + slab * 8]);
        *(short8*)&lsB[(slab * 128 + row) * 8] = cvt8(&W32[(size_t)(n0 + row) * DM + k0 + slab * 8]);
      }
    } else {
      const u16* X16 = (const u16*)Xv;
      const u16* W16 = (const u16*)Wp;
#pragma unroll
      for (int r = 0; r < 2; ++r) {
        const int row = r * 64 + lane;
        gl_lds16(&X16[(size_t)(m0 + row) * DM + k0 + wv * 8], &lsA[(wv * 128 + row) * 8]);
        gl_lds16(&W16[(size_t)(n0 + row) * DM + k0 + wv * 8], &lsB[(wv * 128 + row) * 8]);
      }
    }
    __syncthreads();
    short8 af[4], bf[4];
#pragma unroll
    for (int mt = 0; mt < 4; ++mt)
      af[mt] = *(const short8*)&lsA[(lq * 128 + wm * 64 + mt * 16 + li) * 8];
#pragma unroll
    for (int nt = 0; nt < 4; ++nt)
      bf[nt] = *(const short8*)&lsB[(lq * 128 + wn * 64 + nt * 16 + li) * 8];
#pragma unroll
    for (int mt = 0; mt < 4; ++mt)
#pragma unroll
      for (int nt = 0; nt < 4; ++nt)
        acc[mt][nt] = __builtin_amdgcn_mfma_f32_16x16x32_bf16(af[mt], bf[nt], acc[mt][nt], 0, 0, 0);
    __syncthreads();
  }

  float bs[4];
#pragma unroll
  for (int nt = 0; nt < 4; ++nt) bs[nt] = bias[n0 + wn * 64 + nt * 16 + li];

  if (z != 2) {
    // q/k: [B,T,D] row-major; wave writes 4x32B forming 128B regions
    const float scale = (z == 0) ? 0.125f : 1.0f;
    u16* dst = (z == 0) ? q : k;
#pragma unroll
    for (int mt = 0; mt < 4; ++mt) {
      const int mbase = m0 + wm * 64 + mt * 16 + lq * 4;
#pragma unroll
      for (int nt = 0; nt < 4; ++nt) {
        const int n = n0 + wn * 64 + nt * 16 + li;
#pragma unroll
        for (int r = 0; r < 4; ++r)
          dst[(size_t)(mbase + r) * DM + n] = f2bf((acc[mt][nt][r] + bs[nt]) * scale);
      }
    }
  } else {
    // v: [B,H,hd,T]. Phase A: acc -> smem[n][m] (bf16, b64 writes).
#pragma unroll
    for (int mt = 0; mt < 4; ++mt) {
      const int mcol = wm * 64 + mt * 16 + lq * 4;       // local m, 4 consecutive
#pragma unroll
      for (int nt = 0; nt < 4; ++nt) {
        const int nrow = wn * 64 + nt * 16 + li;          // local n
        u16 pk[4];
#pragma unroll
        for (int r = 0; r < 4; ++r) pk[r] = f2bf(acc[mt][nt][r] + bs[nt]);
        *(short4v*)&smem[nrow * 136 + mcol] = *(const short4v*)pk;
      }
    }
    __syncthreads();
    // Phase B: coalesced stores, 256B per (h,d) row chunk
    const int b = m0 >> 11;
    const int t0 = m0 & (T_SEQ - 1);
#pragma unroll
    for (int p = 0; p < 8; ++p) {
      const int n = p * 16 + (tid >> 4);                  // local n row
      const int c = tid & 15;                              // 16B chunk along m
      const short8 val = *(const short8*)&smem[n * 136 + c * 8];
      const int ng = n0 + n;
      const int h = ng >> 6, d = ng & 63;
      *(short8*)&v[((size_t)(b * NH + h) * HD + d) * T_SEQ + t0 + c * 8] = val;
    }
  }
}

// ---------------- fused attention ----------------
// Block = (b, h, 128 t). K/V tiles via dbuf gl_lds (XOR-swizzled); f via
// register-prefetch pipeline (one iter ahead); pP wave-private swizzled LDS.
__global__ __launch_bounds__(256, 2) void attn_kernel(
    const u16* __restrict__ q, const u16* __restrict__ k,
    const u16* __restrict__ v, const void* __restrict__ fv,
    int isf32, u16* __restrict__ ao)
{
  __shared__ alignas(16) u16 Kl[2][8192];
  __shared__ alignas(16) u16 Vl[2][8192];
  __shared__ alignas(16) u16 pPf[4][2048];

  const int tid = threadIdx.x;
  const int w = tid >> 6;
  const int lane = tid & 63;
  const int lq = lane >> 4, li = lane & 15;

  const int t0 = blockIdx.x * 128;
  const int h = blockIdx.y;
  const int b = blockIdx.z;

  const u16* qh = q + (size_t)b * T_SEQ * DM + h * HD;   // [T][DM] slice
  const u16* kh = k + (size_t)b * T_SEQ * DM + h * HD;
  const u16* vh = v + (size_t)(b * NH + h) * HD * T_SEQ; // [hd][T]

  short8 qf[2][2];
#pragma unroll
  for (int g = 0; g < 2; ++g)
#pragma unroll
    for (int kk = 0; kk < 2; ++kk)
      qf[g][kk] = *(const short8*)&qh[(size_t)(t0 + w * 32 + g * 16 + li) * DM + kk * 32 + lq * 8];

  f32x4 oacc[2][4];
#pragma unroll
  for (int g = 0; g < 2; ++g)
#pragma unroll
    for (int j = 0; j < 4; j++) oacc[g][j] = (f32x4){0.f, 0.f, 0.f, 0.f};
  float den[2] = {0.f, 0.f};

  const int tg0 = t0 + w * 32 + li;   // g adds +16

#define STAGE_TILE(S0, BUF)                                                      \
  {                                                                              \
    const u16* gK = kh + (size_t)(S0) * DM;                                      \
    const u16* gV = vh + (S0);                                                   \
    u16* Kb = &Kl[BUF][0];                                                       \
    u16* Vb = &Vl[BUF][0];                                                       \
    _Pragma("unroll")                                                            \
    for (int r = 0; r < 4; ++r) {                                                \
      const int L = (w * 4 + r) * 64 + lane;                                     \
      const int sl = L >> 3, jx = L & 7, j = jx ^ (sl & 7);                      \
      gl_lds16(gK + (size_t)sl * DM + j * 8, Kb + (size_t)L * 8);                \
      const int d = L >> 4, scx = L & 15, sc = scx ^ (d & 15);                   \
      gl_lds16(gV + (size_t)d * T_SEQ + sc * 8, Vb + (size_t)L * 8);             \
    }                                                                            \
  }

#define LOAD_F(S0, FB)                                                           \
  if (isf32) {                                                                   \
    const float* f32p = (const float*)fv + (size_t)b * T_SEQ * T_SEQ;            \
    _Pragma("unroll")                                                            \
    for (int g = 0; g < 2; ++g)                                                  \
      _Pragma("unroll")                                                          \
      for (int mt = 0; mt < 8; ++mt) {                                           \
        const f32x4 fr = *(const f32x4*)&f32p[(size_t)(tg0 + g * 16) * T_SEQ + (S0) + mt * 16 + lq * 4]; \
        short4v pk;                                                              \
        pk[0] = (short)f2bf(fr[0]); pk[1] = (short)f2bf(fr[1]);                  \
        pk[2] = (short)f2bf(fr[2]); pk[3] = (short)f2bf(fr[3]);                  \
        FB[g][mt] = pk;                                                          \
      }                                                                          \
  } else {                                                                       \
    const u16* f16p = (const u16*)fv + (size_t)b * T_SEQ * T_SEQ;                \
    _Pragma("unroll")                                                            \
    for (int g = 0; g < 2; ++g)                                                  \
      _Pragma("unroll")                                                          \
      for (int mt = 0; mt < 8; ++mt)                                             \
        FB[g][mt] = *(const short4v*)&f16p[(size_t)(tg0 + g * 16) * T_SEQ + (S0) + mt * 16 + lq * 4]; \
  }

  // iteration body: consumes FCUR, prefetches into FNXT
#define ITER_BODY(IT, FCUR, FNXT)                                                \
  {                                                                              \
    const int cur = (IT) & 1;                                                    \
    const int s0 = (IT) * 128;                                                   \
    if ((IT) < 15) {                                                             \
      STAGE_TILE(s0 + 128, cur ^ 1)                                              \
      LOAD_F(s0 + 128, FNXT)                                                     \
    }                                                                            \
    const u16* Kb = &Kl[cur][0];                                                 \
    const u16* Vb = &Vl[cur][0];                                                 \
    short8 kf[2][8];                                                             \
    _Pragma("unroll")                                                            \
    for (int kk = 0; kk < 2; ++kk)                                               \
      _Pragma("unroll")                                                          \
      for (int mt = 0; mt < 8; ++mt) {                                           \
        const int sl = mt * 16 + li;                                             \
        const int c = sl * 8 + ((kk * 4 + lq) ^ (sl & 7));                       \
        kf[kk][mt] = *(const short8*)&Kb[(size_t)c * 8];                         \
      }                                                                          \
    short8 vf[4][4];                                                             \
    _Pragma("unroll")                                                            \
    for (int kk = 0; kk < 4; ++kk)                                               \
      _Pragma("unroll")                                                          \
      for (int dn = 0; dn < 4; ++dn) {                                           \
        const int d = dn * 16 + li;                                              \
        const int c = d * 16 + ((kk * 4 + lq) ^ (d & 15));                       \
        vf[kk][dn] = *(const short8*)&Vb[(size_t)c * 8];                         \
      }                                                                          \
    u16* pw = &pPf[w][0];                                                        \
    _Pragma("unroll")                                                            \
    for (int g = 0; g < 2; ++g) {                                                \
      f32x4 sacc[8];                                                             \
      _Pragma("unroll")                                                          \
      for (int mt = 0; mt < 8; ++mt) sacc[mt] = (f32x4){0.f, 0.f, 0.f, 0.f};     \
      _Pragma("unroll")                                                          \
      for (int kk = 0; kk < 2; ++kk)                                             \
        _Pragma("unroll")                                                        \
        for (int mt = 0; mt < 8; ++mt)                                           \
          sacc[mt] = __builtin_amdgcn_mfma_f32_16x16x32_bf16(kf[kk][mt], qf[g][kk], sacc[mt], 0, 0, 0); \
      _Pragma("unroll")                                                          \
      for (int mt = 0; mt < 8; ++mt) {                                           \
        const short4v fr = FCUR[g][mt];                                          \
        u16 pk[4];                                                               \
        _Pragma("unroll")                                                        \
        for (int r = 0; r < 4; ++r) {                                            \
          const float e = __expf(sacc[mt][r]);                                   \
          const float p = b2f((u16)fr[r]) * e;                                   \
          den[g] += p;                                                           \
          pk[r] = f2bf(p);                                                       \
        }                                                                        \
        const int c8 = (mt * 4 + lq) ^ ((li & 7) << 1);                          \
        *(short4v*)&pw[li * 128 + c8 * 4] = *(const short4v*)pk;                 \
      }                                                                          \
      _Pragma("unroll")                                                          \
      for (int kk = 0; kk < 4; ++kk) {                                           \
        const int c8 = ((kk << 3) + (lq << 1)) ^ ((li & 7) << 1);                \
        const short8 pf = *(const short8*)&pw[li * 128 + c8 * 4];                \
        _Pragma("unroll")                                                        \
        for (int dn = 0; dn < 4; ++dn)                                           \
          oacc[g][dn] = __builtin_amdgcn_mfma_f32_16x16x32_bf16(pf, vf[kk][dn], oacc[g][dn], 0, 0, 0); \
      }                                                                          \
    }                                                                            \
    __syncthreads();                                                             \
  }

  short4v fA[2][8], fB[2][8];
  STAGE_TILE(0, 0)
  LOAD_F(0, fA)
  __syncthreads();

  for (int it2 = 0; it2 < 16; it2 += 2) {
    ITER_BODY(it2,     fA, fB)
    ITER_BODY(it2 + 1, fB, fA)
  }

#pragma unroll
  for (int g = 0; g < 2; ++g) {
    den[g] += __shfl_xor(den[g], 16, 64);
    den[g] += __shfl_xor(den[g], 32, 64);
  }

#pragma unroll
  for (int g = 0; g < 2; ++g) {
#pragma unroll
    for (int r = 0; r < 4; ++r) {
      const float rd = 1.0f / __shfl(den[g], lq * 4 + r, 64);
      const int t = t0 + w * 32 + g * 16 + lq * 4 + r;
#pragma unroll
      for (int dn = 0; dn < 4; ++dn)
        ao[(size_t)(b * T_SEQ + t) * DM + h * HD + dn * 16 + li] = f2bf(oacc[g][dn][r] * rd);
    }
  }
#undef ITER_BODY
#undef LOAD_F
#undef STAGE_TILE
}

// ---------------- output projection GEMM (fp32 output) ----------------
__global__ __launch_bounds__(256, 4) void oproj_kernel(
    const u16* __restrict__ A, const void* __restrict__ Wov,
    const float* __restrict__ bo, int isf32, float* __restrict__ out)
{
  __shared__ alignas(16) short lsA[4][128][8];
  __shared__ alignas(16) short lsB[4][128][8];

  const int tid = threadIdx.x;
  const int lane = tid & 63;
  const int wv = tid >> 6;
  const int lq = lane >> 4, li = lane & 15;
  const int wm = wv >> 1, wn = wv & 1;

  const int m0 = blockIdx.y * 128;
  const int n0 = blockIdx.x * 128;

  f32x4 acc[4][4];
#pragma unroll
  for (int i = 0; i < 4; i++)
#pragma unroll
    for (int j = 0; j < 4; j++) acc[i][j] = (f32x4){0.f, 0.f, 0.f, 0.f};

  for (int k0 = 0; k0 < DM; k0 += 32) {
#pragma unroll
    for (int r = 0; r < 2; ++r) {
      const int row = r * 64 + lane;
      gl_lds16(&A[(size_t)(m0 + row) * DM + k0 + wv * 8], &lsA[wv][row][0]);
    }
    if (isf32) {
      const float* W32 = (const float*)Wov;
#pragma unroll
      for (int r = 0; r < 2; ++r) {
        const int idx = tid + 256 * r;
        const int row = idx >> 2, slab = idx & 3;
        *(short8*)&lsB[slab][row][0] = cvt8(&W32[(size_t)(n0 + row) * DM + k0 + slab * 8]);
      }
    } else {
      const u16* W16 = (const u16*)Wov;
#pragma unroll
      for (int r = 0; r < 2; ++r) {
        const int row = r * 64 + lane;
        gl_lds16(&W16[(size_t)(n0 + row) * DM + k0 + wv * 8], &lsB[wv][row][0]);
      }
    }
    __syncthreads();
    short8 af[4], bf[4];
#pragma unroll
    for (int mt = 0; mt < 4; ++mt)
      af[mt] = *(const short8*)&lsA[lq][wm * 64 + mt * 16 + li][0];
#pragma unroll
    for (int nt = 0; nt < 4; ++nt)
      bf[nt] = *(const short8*)&lsB[lq][wn * 64 + nt * 16 + li][0];
#pragma unroll
    for (int mt = 0; mt < 4; ++mt)
#pragma unroll
      for (int nt = 0; nt < 4; ++nt)
        acc[mt][nt] = __builtin_amdgcn_mfma_f32_16x16x32_bf16(af[mt], bf[nt], acc[mt][nt], 0, 0, 0);
    __syncthreads();
  }

  float bs[4];
#pragma unroll
  for (int nt = 0; nt < 4; ++nt) bs[nt] = bo[n0 + wn * 64 + nt * 16 + li];

#pragma unroll
  for (int mt = 0; mt < 4; ++mt) {
    const int mbase = m0 + wm * 64 + mt * 16 + lq * 4;
#pragma unroll
    for (int nt = 0; nt < 4; ++nt) {
      const int n = n0 + wn * 64 + nt * 16 + li;
#pragma unroll
      for (int r = 0; r < 4; ++r)
        out[(size_t)(mbase + r) * DM + n] = acc[mt][nt][r] + bs[nt];
    }
  }
}

extern "C" void kernel_launch(void* const* d_in, const int* in_sizes, int n_in,
                              void* d_out, int out_size, void* d_ws, size_t ws_size,
                              hipStream_t stream) {
  (void)in_sizes; (void)n_in; (void)out_size;
  const float* hs = (const float*)d_in[0];
  const float* fa = (const float*)d_in[1];
  const float* Wq = (const float*)d_in[2];
  const float* bq = (const float*)d_in[3];
  const float* Wk = (const float*)d_in[4];
  const float* bk = (const float*)d_in[5];
  const float* Wv = (const float*)d_in[6];
  const float* bv = (const float*)d_in[7];
  const float* Wo = (const float*)d_in[8];
  const float* bo = (const float*)d_in[9];
  float* out = (float*)d_out;

  const size_t NEED = 256 + 2u * (8388608u + 4194304u + 4u * 1048576u + 4u * 4194304u);
  char* base = (char*)d_ws + 256;
  if (ws_size >= NEED) {
    u16* fb  = (u16*)base;
    u16* hsb = fb + 8388608u;
    u16* Wqb = hsb + 4194304u;
    u16* Wkb = Wqb + 1048576u;
    u16* Wvb = Wkb + 1048576u;
    u16* Wob = Wvb + 1048576u;
    u16* qw  = Wob + 1048576u;
    u16* kw  = qw + 4194304u;
    u16* vw  = kw + 4194304u;
    u16* aw  = vw + 4194304u;
    cvt_kernel<<<8192, 256, 0, stream>>>(hs, fa, Wq, Wk, Wv, Wo, hsb, fb, Wqb, Wkb, Wvb, Wob);
    qkv_kernel<<<dim3(8, 32, 3), 256, 0, stream>>>(hsb, Wqb, bq, Wkb, bk, Wvb, bv, 0, qw, kw, vw);
    attn_kernel<<<dim3(16, 16, 2), 256, 0, stream>>>(qw, kw, vw, fb, 0, aw);
    oproj_kernel<<<dim3(8, 32, 1), 256, 0, stream>>>(aw, Wob, bo, 0, out);
  } else {
    u16* qw = (u16*)base;
    u16* kw = qw + 4194304u;
    u16* vw = kw + 4194304u;
    u16* aw = vw + 4194304u;
    qkv_kernel<<<dim3(8, 32, 3), 256, 0, stream>>>(hs, Wq, bq, Wk, bk, Wv, bv, 1, qw, kw, vw);
    attn_kernel<<<dim3(16, 16, 2), 256, 0, stream>>>(qw, kw, vw, fa, 1, aw);
    oproj_kernel<<<dim3(8, 32, 1), 256, 0, stream>>>(aw, Wo, bo, 1, out);
  }
}

// Round 8
// 292.936 us; speedup vs baseline: 1.4676x; 1.4676x over previous
//
#include <hip/hip_runtime.h>
#include <stdint.h>

// BartAttention fused: out = ((f*exp(QK^T))/rowsum) @ V heads -> @ Wo + bo
// B=2 T=2048 D=1024 H=16 hd=64. Inputs fp32, output fp32, intermediates bf16.
// R8: R6 attn structure + single-buffered f register prefetch (no loop-carried
// dbuf -> no spills), QK hoisted for both groups, vf just-in-time, coalesced
// 16B epilogue stores via swizzled LDS transpose.

typedef __attribute__((ext_vector_type(8))) short short8;
typedef __attribute__((ext_vector_type(4))) short short4v;
typedef __attribute__((ext_vector_type(4))) float f32x4;
typedef unsigned short u16;

#define T_SEQ 2048
#define NH    16
#define HD    64
#define DM    1024

__device__ __forceinline__ float b2f(u16 h) {
  union { unsigned u; float f; } v; v.u = ((unsigned)h) << 16; return v.f;
}
__device__ __forceinline__ u16 f2bf(float x) {  // round-to-nearest-even
  union { float f; unsigned u; } v; v.f = x;
  unsigned r = v.u + 0x7fffu + ((v.u >> 16) & 1u);
  return (u16)(r >> 16);
}
__device__ __forceinline__ short8 cvt8(const float* p) {
  const f32x4 a = *(const f32x4*)p;
  const f32x4 b = *(const f32x4*)(p + 4);
  short8 o;
  o[0] = (short)f2bf(a[0]); o[1] = (short)f2bf(a[1]);
  o[2] = (short)f2bf(a[2]); o[3] = (short)f2bf(a[3]);
  o[4] = (short)f2bf(b[0]); o[5] = (short)f2bf(b[1]);
  o[6] = (short)f2bf(b[2]); o[7] = (short)f2bf(b[3]);
  return o;
}
__device__ __forceinline__ void gl_lds16(const void* g, void* l) {
  __builtin_amdgcn_global_load_lds(
      (const __attribute__((address_space(1))) void*)g,
      (__attribute__((address_space(3))) void*)l, 16, 0, 0);
}

// ---------------- fp32 -> bf16 prepass ----------------
#define HS_CH 524288u
#define F_CH  1048576u
#define W_CH  131072u
__global__ void cvt_kernel(const float* __restrict__ hs, const float* __restrict__ f,
                           const float* __restrict__ Wq, const float* __restrict__ Wk,
                           const float* __restrict__ Wv, const float* __restrict__ Wo,
                           u16* __restrict__ hsb, u16* __restrict__ fb,
                           u16* __restrict__ Wqb, u16* __restrict__ Wkb,
                           u16* __restrict__ Wvb, u16* __restrict__ Wob) {
  unsigned c = blockIdx.x * 256 + threadIdx.x;
  const float* s; u16* d; unsigned off;
  if (c < HS_CH)                       { s = hs; d = hsb; off = c; }
  else if ((c -= HS_CH) < F_CH)        { s = f;  d = fb;  off = c; }
  else if ((c -= F_CH) < W_CH)         { s = Wq; d = Wqb; off = c; }
  else if ((c -= W_CH) < W_CH)         { s = Wk; d = Wkb; off = c; }
  else if ((c -= W_CH) < W_CH)         { s = Wv; d = Wvb; off = c; }
  else                                 { s = Wo; d = Wob; off = c - W_CH; }
  *(short8*)&d[(size_t)off * 8] = cvt8(&s[(size_t)off * 8]);
}

// ---------------- QKV projection GEMM (unchanged from R7) ----------------
__global__ __launch_bounds__(256, 4) void qkv_kernel(
    const void* __restrict__ Xv,
    const void* __restrict__ Wqv, const float* __restrict__ bq,
    const void* __restrict__ Wkv, const float* __restrict__ bk,
    const void* __restrict__ Wvv, const float* __restrict__ bv,
    int isf32,
    u16* __restrict__ q, u16* __restrict__ k, u16* __restrict__ v)
{
  const int z = blockIdx.z;
  const void* Wp = (z == 0) ? Wqv : (z == 1) ? Wkv : Wvv;
  const float* bias = (z == 0) ? bq : (z == 1) ? bk : bv;

  __shared__ alignas(16) u16 smem[17408];
  u16* lsA = smem;
  u16* lsB = smem + 4096;

  const int tid = threadIdx.x;
  const int lane = tid & 63;
  const int wv = tid >> 6;
  const int lq = lane >> 4, li = lane & 15;
  const int wm = wv >> 1, wn = wv & 1;

  const int m0 = blockIdx.y * 128;
  const int n0 = blockIdx.x * 128;

  f32x4 acc[4][4];
#pragma unroll
  for (int i = 0; i < 4; i++)
#pragma unroll
    for (int j = 0; j < 4; j++) acc[i][j] = (f32x4){0.f, 0.f, 0.f, 0.f};

  for (int k0 = 0; k0 < DM; k0 += 32) {
    if (isf32) {
      const float* X32 = (const float*)Xv;
      const float* W32 = (const float*)Wp;
#pragma unroll
      for (int r = 0; r < 2; ++r) {
        const int idx = tid + 256 * r;
        const int row = idx >> 2, slab = idx & 3;
        *(short8*)&lsA[(slab * 128 + row) * 8] = cvt8(&X32[(size_t)(m0 + row) * DM + k0 + slab * 8]);
        *(short8*)&lsB[(slab * 128 + row) * 8] = cvt8(&W32[(size_t)(n0 + row) * DM + k0 + slab * 8]);
      }
    } else {
      const u16* X16 = (const u16*)Xv;
      const u16* W16 = (const u16*)Wp;
#pragma unroll
      for (int r = 0; r < 2; ++r) {
        const int row = r * 64 + lane;
        gl_lds16(&X16[(size_t)(m0 + row) * DM + k0 + wv * 8], &lsA[(wv * 128 + row) * 8]);
        gl_lds16(&W16[(size_t)(n0 + row) * DM + k0 + wv * 8], &lsB[(wv * 128 + row) * 8]);
      }
    }
    __syncthreads();
    short8 af[4], bf[4];
#pragma unroll
    for (int mt = 0; mt < 4; ++mt)
      af[mt] = *(const short8*)&lsA[(lq * 128 + wm * 64 + mt * 16 + li) * 8];
#pragma unroll
    for (int nt = 0; nt < 4; ++nt)
      bf[nt] = *(const short8*)&lsB[(lq * 128 + wn * 64 + nt * 16 + li) * 8];
#pragma unroll
    for (int mt = 0; mt < 4; ++mt)
#pragma unroll
      for (int nt = 0; nt < 4; ++nt)
        acc[mt][nt] = __builtin_amdgcn_mfma_f32_16x16x32_bf16(af[mt], bf[nt], acc[mt][nt], 0, 0, 0);
    __syncthreads();
  }

  float bs[4];
#pragma unroll
  for (int nt = 0; nt < 4; ++nt) bs[nt] = bias[n0 + wn * 64 + nt * 16 + li];

  if (z != 2) {
    const float scale = (z == 0) ? 0.125f : 1.0f;
    u16* dst = (z == 0) ? q : k;
#pragma unroll
    for (int mt = 0; mt < 4; ++mt) {
      const int mbase = m0 + wm * 64 + mt * 16 + lq * 4;
#pragma unroll
      for (int nt = 0; nt < 4; ++nt) {
        const int n = n0 + wn * 64 + nt * 16 + li;
#pragma unroll
        for (int r = 0; r < 4; ++r)
          dst[(size_t)(mbase + r) * DM + n] = f2bf((acc[mt][nt][r] + bs[nt]) * scale);
      }
    }
  } else {
#pragma unroll
    for (int mt = 0; mt < 4; ++mt) {
      const int mcol = wm * 64 + mt * 16 + lq * 4;
#pragma unroll
      for (int nt = 0; nt < 4; ++nt) {
        const int nrow = wn * 64 + nt * 16 + li;
        u16 pk[4];
#pragma unroll
        for (int r = 0; r < 4; ++r) pk[r] = f2bf(acc[mt][nt][r] + bs[nt]);
        *(short4v*)&smem[nrow * 136 + mcol] = *(const short4v*)pk;
      }
    }
    __syncthreads();
    const int b = m0 >> 11;
    const int t0 = m0 & (T_SEQ - 1);
#pragma unroll
    for (int p = 0; p < 8; ++p) {
      const int n = p * 16 + (tid >> 4);
      const int c = tid & 15;
      const short8 val = *(const short8*)&smem[n * 136 + c * 8];
      const int ng = n0 + n;
      const int h = ng >> 6, d = ng & 63;
      *(short8*)&v[((size_t)(b * NH + h) * HD + d) * T_SEQ + t0 + c * 8] = val;
    }
  }
}

// ---------------- fused attention ----------------
// Block = (b, h, 128 t); 4 waves x 32 t (2 groups of 16).
// K/V: dbuf gl_lds staging (XOR-swizzled). f: single-buffer register prefetch
// issued at top of iter. QK for both groups first (sacc[2][8] in acc file),
// then per-g P (exp) + PV (vf just-in-time). Epilogue via swizzled LDS
// transpose -> 16B global stores.
__global__ __launch_bounds__(256, 2) void attn_kernel(
    const u16* __restrict__ q, const u16* __restrict__ k,
    const u16* __restrict__ v, const void* __restrict__ fv,
    int isf32, u16* __restrict__ ao)
{
  __shared__ alignas(16) u16 Kl[2][8192];
  __shared__ alignas(16) u16 Vl[2][8192];
  __shared__ alignas(16) u16 pPf[4][2048];

  const int tid = threadIdx.x;
  const int w = tid >> 6;
  const int lane = tid & 63;
  const int lq = lane >> 4, li = lane & 15;

  const int t0 = blockIdx.x * 128;
  const int h = blockIdx.y;
  const int b = blockIdx.z;

  const u16* qh = q + (size_t)b * T_SEQ * DM + h * HD;   // [T][DM] slice
  const u16* kh = k + (size_t)b * T_SEQ * DM + h * HD;
  const u16* vh = v + (size_t)(b * NH + h) * HD * T_SEQ; // [hd][T]

  short8 qf[2][2];
#pragma unroll
  for (int g = 0; g < 2; ++g)
#pragma unroll
    for (int kk = 0; kk < 2; ++kk)
      qf[g][kk] = *(const short8*)&qh[(size_t)(t0 + w * 32 + g * 16 + li) * DM + kk * 32 + lq * 8];

  f32x4 oacc[2][4];
#pragma unroll
  for (int g = 0; g < 2; ++g)
#pragma unroll
    for (int j = 0; j < 4; j++) oacc[g][j] = (f32x4){0.f, 0.f, 0.f, 0.f};
  float den[2] = {0.f, 0.f};

  const int tg0 = t0 + w * 32 + li;

#define STAGE_TILE(S0, BUF)                                                      \
  {                                                                              \
    const u16* gK = kh + (size_t)(S0) * DM;                                      \
    const u16* gV = vh + (S0);                                                   \
    u16* Kb = &Kl[BUF][0];                                                       \
    u16* Vb = &Vl[BUF][0];                                                       \
    _Pragma("unroll")                                                            \
    for (int r = 0; r < 4; ++r) {                                                \
      const int L = (w * 4 + r) * 64 + lane;                                     \
      const int sl = L >> 3, jx = L & 7, j = jx ^ (sl & 7);                      \
      gl_lds16(gK + (size_t)sl * DM + j * 8, Kb + (size_t)L * 8);                \
      const int d = L >> 4, scx = L & 15, sc = scx ^ (d & 15);                   \
      gl_lds16(gV + (size_t)d * T_SEQ + sc * 8, Vb + (size_t)L * 8);             \
    }                                                                            \
  }

  STAGE_TILE(0, 0)
  __syncthreads();

  for (int it = 0; it < 16; ++it) {
    const int cur = it & 1;
    const int s0 = it * 128;
    if (it < 15) STAGE_TILE(s0 + 128, cur ^ 1)

    // f for THIS iter: issue early (covered by kf LDS reads + QK MFMAs)
    short4v fr[2][8];
    if (isf32) {
      const float* f32p = (const float*)fv + (size_t)b * T_SEQ * T_SEQ;
#pragma unroll
      for (int g = 0; g < 2; ++g)
#pragma unroll
        for (int mt = 0; mt < 8; ++mt) {
          const f32x4 fx = *(const f32x4*)&f32p[(size_t)(tg0 + g * 16) * T_SEQ + s0 + mt * 16 + lq * 4];
          short4v pk;
          pk[0] = (short)f2bf(fx[0]); pk[1] = (short)f2bf(fx[1]);
          pk[2] = (short)f2bf(fx[2]); pk[3] = (short)f2bf(fx[3]);
          fr[g][mt] = pk;
        }
    } else {
      const u16* f16p = (const u16*)fv + (size_t)b * T_SEQ * T_SEQ;
#pragma unroll
      for (int g = 0; g < 2; ++g)
#pragma unroll
        for (int mt = 0; mt < 8; ++mt)
          fr[g][mt] = *(const short4v*)&f16p[(size_t)(tg0 + g * 16) * T_SEQ + s0 + mt * 16 + lq * 4];
    }

    const u16* Kb = &Kl[cur][0];
    const u16* Vb = &Vl[cur][0];

    // K frags from LDS
    short8 kf[2][8];
#pragma unroll
    for (int kk = 0; kk < 2; ++kk)
#pragma unroll
      for (int mt = 0; mt < 8; ++mt) {
        const int sl = mt * 16 + li;
        const int c = sl * 8 + ((kk * 4 + lq) ^ (sl & 7));
        kf[kk][mt] = *(const short8*)&Kb[(size_t)c * 8];
      }

    // QK for both groups
    f32x4 sacc[2][8];
#pragma unroll
    for (int g = 0; g < 2; ++g)
#pragma unroll
      for (int mt = 0; mt < 8; ++mt) sacc[g][mt] = (f32x4){0.f, 0.f, 0.f, 0.f};
#pragma unroll
    for (int kk = 0; kk < 2; ++kk)
#pragma unroll
      for (int mt = 0; mt < 8; ++mt) {
        sacc[0][mt] = __builtin_amdgcn_mfma_f32_16x16x32_bf16(kf[kk][mt], qf[0][kk], sacc[0][mt], 0, 0, 0);
        sacc[1][mt] = __builtin_amdgcn_mfma_f32_16x16x32_bf16(kf[kk][mt], qf[1][kk], sacc[1][mt], 0, 0, 0);
      }

    u16* pw = &pPf[w][0];
#pragma unroll
    for (int g = 0; g < 2; ++g) {
      // P = f * exp(S) -> wave-private pP (swizzled 8B chunks)
#pragma unroll
      for (int mt = 0; mt < 8; ++mt) {
        const short4v fx = fr[g][mt];
        u16 pk[4];
#pragma unroll
        for (int r = 0; r < 4; ++r) {
          const float e = __expf(sacc[g][mt][r]);
          const float p = b2f((u16)fx[r]) * e;
          den[g] += p;
          pk[r] = f2bf(p);
        }
        const int c8 = (mt * 4 + lq) ^ ((li & 7) << 1);
        *(short4v*)&pw[li * 128 + c8 * 4] = *(const short4v*)pk;
      }
      // O += P @ V (vf just-in-time per kk)
#pragma unroll
      for (int kk = 0; kk < 4; ++kk) {
        const int c8 = ((kk << 3) + (lq << 1)) ^ ((li & 7) << 1);
        const short8 pf = *(const short8*)&pw[li * 128 + c8 * 4];
#pragma unroll
        for (int dn = 0; dn < 4; ++dn) {
          const int d = dn * 16 + li;
          const int c = d * 16 + ((kk * 4 + lq) ^ (d & 15));
          const short8 vf = *(const short8*)&Vb[(size_t)c * 8];
          oacc[g][dn] = __builtin_amdgcn_mfma_f32_16x16x32_bf16(pf, vf, oacc[g][dn], 0, 0, 0);
        }
      }
    }
    __syncthreads();
  }

  // den reduce across quads (lanes {li, li+16, li+32, li+48})
#pragma unroll
  for (int g = 0; g < 2; ++g) {
    den[g] += __shfl_xor(den[g], 16, 64);
    den[g] += __shfl_xor(den[g], 32, 64);
  }

  // scale + transpose into wave-private pP ([32 t][64 d], 8-chunk XOR swizzle)
  u16* pw = &pPf[w][0];
#pragma unroll
  for (int g = 0; g < 2; ++g)
#pragma unroll
    for (int r = 0; r < 4; ++r) {
      const float rd = 1.0f / __shfl(den[g], lq * 4 + r, 64);
      const int trow = g * 16 + lq * 4 + r;
#pragma unroll
      for (int dn = 0; dn < 4; ++dn) {
        const int d = dn * 16 + li;
        const int ch = ((d >> 3) ^ (trow & 7));
        pw[trow * 64 + ch * 8 + (d & 7)] = f2bf(oacc[g][dn][r] * rd);
      }
    }
  // wave-private: no barrier. Coalesced 16B stores (4 per lane).
  const int rloc = lane >> 1, half = lane & 1;
#pragma unroll
  for (int c = 0; c < 4; ++c) {
    const int ch = ((half * 4 + c) ^ (rloc & 7));
    const short8 vv = *(const short8*)&pw[rloc * 64 + ch * 8];
    *(short8*)&ao[(size_t)(b * T_SEQ + t0 + w * 32 + rloc) * DM + h * HD + half * 32 + c * 8] = vv;
  }
#undef STAGE_TILE
}

// ---------------- output projection GEMM (fp32 output, unchanged) -----------
__global__ __launch_bounds__(256, 4) void oproj_kernel(
    const u16* __restrict__ A, const void* __restrict__ Wov,
    const float* __restrict__ bo, int isf32, float* __restrict__ out)
{
  __shared__ alignas(16) short lsA[4][128][8];
  __shared__ alignas(16) short lsB[4][128][8];

  const int tid = threadIdx.x;
  const int lane = tid & 63;
  const int wv = tid >> 6;
  const int lq = lane >> 4, li = lane & 15;
  const int wm = wv >> 1, wn = wv & 1;

  const int m0 = blockIdx.y * 128;
  const int n0 = blockIdx.x * 128;

  f32x4 acc[4][4];
#pragma unroll
  for (int i = 0; i < 4; i++)
#pragma unroll
    for (int j = 0; j < 4; j++) acc[i][j] = (f32x4){0.f, 0.f, 0.f, 0.f};

  for (int k0 = 0; k0 < DM; k0 += 32) {
#pragma unroll
    for (int r = 0; r < 2; ++r) {
      const int row = r * 64 + lane;
      gl_lds16(&A[(size_t)(m0 + row) * DM + k0 + wv * 8], &lsA[wv][row][0]);
    }
    if (isf32) {
      const float* W32 = (const float*)Wov;
#pragma unroll
      for (int r = 0; r < 2; ++r) {
        const int idx = tid + 256 * r;
        const int row = idx >> 2, slab = idx & 3;
        *(short8*)&lsB[slab][row][0] = cvt8(&W32[(size_t)(n0 + row) * DM + k0 + slab * 8]);
      }
    } else {
      const u16* W16 = (const u16*)Wov;
#pragma unroll
      for (int r = 0; r < 2; ++r) {
        const int row = r * 64 + lane;
        gl_lds16(&W16[(size_t)(n0 + row) * DM + k0 + wv * 8], &lsB[wv][row][0]);
      }
    }
    __syncthreads();
    short8 af[4], bf[4];
#pragma unroll
    for (int mt = 0; mt < 4; ++mt)
      af[mt] = *(const short8*)&lsA[lq][wm * 64 + mt * 16 + li][0];
#pragma unroll
    for (int nt = 0; nt < 4; ++nt)
      bf[nt] = *(const short8*)&lsB[lq][wn * 64 + nt * 16 + li][0];
#pragma unroll
    for (int mt = 0; mt < 4; ++mt)
#pragma unroll
      for (int nt = 0; nt < 4; ++nt)
        acc[mt][nt] = __builtin_amdgcn_mfma_f32_16x16x32_bf16(af[mt], bf[nt], acc[mt][nt], 0, 0, 0);
    __syncthreads();
  }

  float bs[4];
#pragma unroll
  for (int nt = 0; nt < 4; ++nt) bs[nt] = bo[n0 + wn * 64 + nt * 16 + li];

#pragma unroll
  for (int mt = 0; mt < 4; ++mt) {
    const int mbase = m0 + wm * 64 + mt * 16 + lq * 4;
#pragma unroll
    for (int nt = 0; nt < 4; ++nt) {
      const int n = n0 + wn * 64 + nt * 16 + li;
#pragma unroll
      for (int r = 0; r < 4; ++r)
        out[(size_t)(mbase + r) * DM + n] = acc[mt][nt][r] + bs[nt];
    }
  }
}

extern "C" void kernel_launch(void* const* d_in, const int* in_sizes, int n_in,
                              void* d_out, int out_size, void* d_ws, size_t ws_size,
                              hipStream_t stream) {
  (void)in_sizes; (void)n_in; (void)out_size;
  const float* hs = (const float*)d_in[0];
  const float* fa = (const float*)d_in[1];
  const float* Wq = (const float*)d_in[2];
  const float* bq = (const float*)d_in[3];
  const float* Wk = (const float*)d_in[4];
  const float* bk = (const float*)d_in[5];
  const float* Wv = (const float*)d_in[6];
  const float* bv = (const float*)d_in[7];
  const float* Wo = (const float*)d_in[8];
  const float* bo = (const float*)d_in[9];
  float* out = (float*)d_out;

  const size_t NEED = 256 + 2u * (8388608u + 4194304u + 4u * 1048576u + 4u * 4194304u);
  char* base = (char*)d_ws + 256;
  if (ws_size >= NEED) {
    u16* fb  = (u16*)base;
    u16* hsb = fb + 8388608u;
    u16* Wqb = hsb + 4194304u;
    u16* Wkb = Wqb + 1048576u;
    u16* Wvb = Wkb + 1048576u;
    u16* Wob = Wvb + 1048576u;
    u16* qw  = Wob + 1048576u;
    u16* kw  = qw + 4194304u;
    u16* vw  = kw + 4194304u;
    u16* aw  = vw + 4194304u;
    cvt_kernel<<<8192, 256, 0, stream>>>(hs, fa, Wq, Wk, Wv, Wo, hsb, fb, Wqb, Wkb, Wvb, Wob);
    qkv_kernel<<<dim3(8, 32, 3), 256, 0, stream>>>(hsb, Wqb, bq, Wkb, bk, Wvb, bv, 0, qw, kw, vw);
    attn_kernel<<<dim3(16, 16, 2), 256, 0, stream>>>(qw, kw, vw, fb, 0, aw);
    oproj_kernel<<<dim3(8, 32, 1), 256, 0, stream>>>(aw, Wob, bo, 0, out);
  } else {
    u16* qw = (u16*)base;
    u16* kw = qw + 4194304u;
    u16* vw = kw + 4194304u;
    u16* aw = vw + 4194304u;
    qkv_kernel<<<dim3(8, 32, 3), 256, 0, stream>>>(hs, Wq, bq, Wk, bk, Wv, bv, 1, qw, kw, vw);
    attn_kernel<<<dim3(16, 16, 2), 256, 0, stream>>>(qw, kw, vw, fa, 1, aw);
    oproj_kernel<<<dim3(8, 32, 1), 256, 0, stream>>>(aw, Wo, bo, 1, out);
  }
}

// Round 9
// 284.141 us; speedup vs baseline: 1.5131x; 1.0310x over previous
//
#include <hip/hip_runtime.h>
#include <stdint.h>

// BartAttention fused: out = ((f*exp(QK^T))/rowsum) @ V heads -> @ Wo + bo
// B=2 T=2048 D=1024 H=16 hd=64. Inputs fp32, output fp32, intermediates bf16.
// R9: attn t=64/s=64 tiles, K/V/f ALL staged via gl_lds (dbuf), P overwrites
// f LDS in place -> 48 KB LDS -> 3 blocks/CU. exp2 with pre-scaled q.

typedef __attribute__((ext_vector_type(8))) short short8;
typedef __attribute__((ext_vector_type(4))) short short4v;
typedef __attribute__((ext_vector_type(4))) float f32x4;
typedef unsigned short u16;

#define T_SEQ 2048
#define NH    16
#define HD    64
#define DM    1024

__device__ __forceinline__ float b2f(u16 h) {
  union { unsigned u; float f; } v; v.u = ((unsigned)h) << 16; return v.f;
}
__device__ __forceinline__ u16 f2bf(float x) {  // round-to-nearest-even
  union { float f; unsigned u; } v; v.f = x;
  unsigned r = v.u + 0x7fffu + ((v.u >> 16) & 1u);
  return (u16)(r >> 16);
}
__device__ __forceinline__ short8 cvt8(const float* p) {
  const f32x4 a = *(const f32x4*)p;
  const f32x4 b = *(const f32x4*)(p + 4);
  short8 o;
  o[0] = (short)f2bf(a[0]); o[1] = (short)f2bf(a[1]);
  o[2] = (short)f2bf(a[2]); o[3] = (short)f2bf(a[3]);
  o[4] = (short)f2bf(b[0]); o[5] = (short)f2bf(b[1]);
  o[6] = (short)f2bf(b[2]); o[7] = (short)f2bf(b[3]);
  return o;
}
__device__ __forceinline__ void gl_lds16(const void* g, void* l) {
  __builtin_amdgcn_global_load_lds(
      (const __attribute__((address_space(1))) void*)g,
      (__attribute__((address_space(3))) void*)l, 16, 0, 0);
}

// q scale: 0.125 (hd^-0.5) * log2(e), so attn uses exp2 directly
#define QSCALE 0.18033688011112042f

// ---------------- fp32 -> bf16 prepass ----------------
#define HS_CH 524288u
#define F_CH  1048576u
#define W_CH  131072u
__global__ void cvt_kernel(const float* __restrict__ hs, const float* __restrict__ f,
                           const float* __restrict__ Wq, const float* __restrict__ Wk,
                           const float* __restrict__ Wv, const float* __restrict__ Wo,
                           u16* __restrict__ hsb, u16* __restrict__ fb,
                           u16* __restrict__ Wqb, u16* __restrict__ Wkb,
                           u16* __restrict__ Wvb, u16* __restrict__ Wob) {
  unsigned c = blockIdx.x * 256 + threadIdx.x;
  const float* s; u16* d; unsigned off;
  if (c < HS_CH)                       { s = hs; d = hsb; off = c; }
  else if ((c -= HS_CH) < F_CH)        { s = f;  d = fb;  off = c; }
  else if ((c -= F_CH) < W_CH)         { s = Wq; d = Wqb; off = c; }
  else if ((c -= W_CH) < W_CH)         { s = Wk; d = Wkb; off = c; }
  else if ((c -= W_CH) < W_CH)         { s = Wv; d = Wvb; off = c; }
  else                                 { s = Wo; d = Wob; off = c - W_CH; }
  *(short8*)&d[(size_t)off * 8] = cvt8(&s[(size_t)off * 8]);
}

// ---------------- QKV projection GEMM ----------------
// q,k -> [B,T,D] (q pre-scaled by QSCALE); v -> [B,H,hd,T] via LDS transpose.
__global__ __launch_bounds__(256, 4) void qkv_kernel(
    const void* __restrict__ Xv,
    const void* __restrict__ Wqv, const float* __restrict__ bq,
    const void* __restrict__ Wkv, const float* __restrict__ bk,
    const void* __restrict__ Wvv, const float* __restrict__ bv,
    int isf32,
    u16* __restrict__ q, u16* __restrict__ k, u16* __restrict__ v)
{
  const int z = blockIdx.z;
  const void* Wp = (z == 0) ? Wqv : (z == 1) ? Wkv : Wvv;
  const float* bias = (z == 0) ? bq : (z == 1) ? bk : bv;

  __shared__ alignas(16) u16 smem[17408];
  u16* lsA = smem;
  u16* lsB = smem + 4096;

  const int tid = threadIdx.x;
  const int lane = tid & 63;
  const int wv = tid >> 6;
  const int lq = lane >> 4, li = lane & 15;
  const int wm = wv >> 1, wn = wv & 1;

  const int m0 = blockIdx.y * 128;
  const int n0 = blockIdx.x * 128;

  f32x4 acc[4][4];
#pragma unroll
  for (int i = 0; i < 4; i++)
#pragma unroll
    for (int j = 0; j < 4; j++) acc[i][j] = (f32x4){0.f, 0.f, 0.f, 0.f};

  for (int k0 = 0; k0 < DM; k0 += 32) {
    if (isf32) {
      const float* X32 = (const float*)Xv;
      const float* W32 = (const float*)Wp;
#pragma unroll
      for (int r = 0; r < 2; ++r) {
        const int idx = tid + 256 * r;
        const int row = idx >> 2, slab = idx & 3;
        *(short8*)&lsA[(slab * 128 + row) * 8] = cvt8(&X32[(size_t)(m0 + row) * DM + k0 + slab * 8]);
        *(short8*)&lsB[(slab * 128 + row) * 8] = cvt8(&W32[(size_t)(n0 + row) * DM + k0 + slab * 8]);
      }
    } else {
      const u16* X16 = (const u16*)Xv;
      const u16* W16 = (const u16*)Wp;
#pragma unroll
      for (int r = 0; r < 2; ++r) {
        const int row = r * 64 + lane;
        gl_lds16(&X16[(size_t)(m0 + row) * DM + k0 + wv * 8], &lsA[(wv * 128 + row) * 8]);
        gl_lds16(&W16[(size_t)(n0 + row) * DM + k0 + wv * 8], &lsB[(wv * 128 + row) * 8]);
      }
    }
    __syncthreads();
    short8 af[4], bf[4];
#pragma unroll
    for (int mt = 0; mt < 4; ++mt)
      af[mt] = *(const short8*)&lsA[(lq * 128 + wm * 64 + mt * 16 + li) * 8];
#pragma unroll
    for (int nt = 0; nt < 4; ++nt)
      bf[nt] = *(const short8*)&lsB[(lq * 128 + wn * 64 + nt * 16 + li) * 8];
#pragma unroll
    for (int mt = 0; mt < 4; ++mt)
#pragma unroll
      for (int nt = 0; nt < 4; ++nt)
        acc[mt][nt] = __builtin_amdgcn_mfma_f32_16x16x32_bf16(af[mt], bf[nt], acc[mt][nt], 0, 0, 0);
    __syncthreads();
  }

  float bs[4];
#pragma unroll
  for (int nt = 0; nt < 4; ++nt) bs[nt] = bias[n0 + wn * 64 + nt * 16 + li];

  if (z != 2) {
    const float scale = (z == 0) ? QSCALE : 1.0f;
    u16* dst = (z == 0) ? q : k;
#pragma unroll
    for (int mt = 0; mt < 4; ++mt) {
      const int mbase = m0 + wm * 64 + mt * 16 + lq * 4;
#pragma unroll
      for (int nt = 0; nt < 4; ++nt) {
        const int n = n0 + wn * 64 + nt * 16 + li;
#pragma unroll
        for (int r = 0; r < 4; ++r)
          dst[(size_t)(mbase + r) * DM + n] = f2bf((acc[mt][nt][r] + bs[nt]) * scale);
      }
    }
  } else {
#pragma unroll
    for (int mt = 0; mt < 4; ++mt) {
      const int mcol = wm * 64 + mt * 16 + lq * 4;
#pragma unroll
      for (int nt = 0; nt < 4; ++nt) {
        const int nrow = wn * 64 + nt * 16 + li;
        u16 pk[4];
#pragma unroll
        for (int r = 0; r < 4; ++r) pk[r] = f2bf(acc[mt][nt][r] + bs[nt]);
        *(short4v*)&smem[nrow * 136 + mcol] = *(const short4v*)pk;
      }
    }
    __syncthreads();
    const int b = m0 >> 11;
    const int t0 = m0 & (T_SEQ - 1);
#pragma unroll
    for (int p = 0; p < 8; ++p) {
      const int n = p * 16 + (tid >> 4);
      const int c = tid & 15;
      const short8 val = *(const short8*)&smem[n * 136 + c * 8];
      const int ng = n0 + n;
      const int h = ng >> 6, d = ng & 63;
      *(short8*)&v[((size_t)(b * NH + h) * HD + d) * T_SEQ + t0 + c * 8] = val;
    }
  }
}

// ---------------- fused attention ----------------
// Block = (b, h, 64 t); 4 waves x 16 t. s-tile 64. K/V/f all staged via
// gl_lds, double-buffered (global-side XOR swizzle, LDS linear chunks).
// P = f*exp2(S) overwrites the f LDS buffer in place (wave-private rows).
__global__ __launch_bounds__(256, 3) void attn_kernel(
    const u16* __restrict__ q, const u16* __restrict__ k,
    const u16* __restrict__ v, const void* __restrict__ fv,
    int isf32, u16* __restrict__ ao)
{
  __shared__ alignas(16) u16 Kl[2][4096];   // chunk L: s=L>>3, slot jx, data j=jx^(s&7)
  __shared__ alignas(16) u16 Vl[2][4096];   // chunk L: d=L>>3, slot jx, data j=jx^(d&7)
  __shared__ alignas(16) u16 Fl[2][4096];   // chunk L: t=L>>3, slot cx, data c=cx^(t&7)

  const int tid = threadIdx.x;
  const int w = tid >> 6;
  const int lane = tid & 63;
  const int lq = lane >> 4, li = lane & 15;

  const int t0 = blockIdx.x * 64;
  const int h = blockIdx.y;
  const int b = blockIdx.z;

  const u16* qh = q + (size_t)b * T_SEQ * DM + h * HD;   // [T][DM]
  const u16* kh = k + (size_t)b * T_SEQ * DM + h * HD;
  const u16* vh = v + (size_t)(b * NH + h) * HD * T_SEQ; // [hd][T]
  const u16* f16p = (const u16*)fv + (size_t)b * T_SEQ * T_SEQ;
  const float* f32p = (const float*)fv + (size_t)b * T_SEQ * T_SEQ;

  // Q fragments (this wave's 16 t)
  short8 qf[2];
#pragma unroll
  for (int kk = 0; kk < 2; ++kk)
    qf[kk] = *(const short8*)&qh[(size_t)(t0 + w * 16 + li) * DM + kk * 32 + lq * 8];

  f32x4 oacc[4];
#pragma unroll
  for (int j = 0; j < 4; j++) oacc[j] = (f32x4){0.f, 0.f, 0.f, 0.f};
  float den = 0.f;

  // stage K/V (+f when bf16) tiles for s-window S0 into buffer BUF
#define STAGE_KV(S0, BUF)                                                        \
  {                                                                              \
    _Pragma("unroll")                                                            \
    for (int r = 0; r < 2; ++r) {                                                \
      const int L = r * 256 + tid;                                               \
      const int row = L >> 3, jx = L & 7;                                        \
      const int j = jx ^ (row & 7);                                              \
      gl_lds16(kh + (size_t)((S0) + row) * DM + j * 8, &Kl[BUF][(size_t)L * 8]); \
      gl_lds16(vh + (size_t)row * T_SEQ + (S0) + j * 8, &Vl[BUF][(size_t)L * 8]);\
      if (!isf32)                                                                \
        gl_lds16(f16p + (size_t)(t0 + row) * T_SEQ + (S0) + j * 8,               \
                 &Fl[BUF][(size_t)L * 8]);                                       \
    }                                                                            \
  }

  STAGE_KV(0, 0)
  __syncthreads();

  for (int it = 0; it < 32; ++it) {
    const int cur = it & 1;
    const int s0 = it * 64;
    if (it < 31) STAGE_KV(s0 + 64, cur ^ 1)

    const u16* Kb = &Kl[cur][0];
    const u16* Vb = &Vl[cur][0];
    u16* Fb = &Fl[cur][0];

    // K fragments (whole 64x64 tile for this wave's QK)
    short8 kf[2][4];
#pragma unroll
    for (int kk = 0; kk < 2; ++kk)
#pragma unroll
      for (int mt = 0; mt < 4; ++mt) {
        const int sl = mt * 16 + li;
        const int c = sl * 8 + ((kk * 4 + lq) ^ (sl & 7));
        kf[kk][mt] = *(const short8*)&Kb[(size_t)c * 8];
      }

    // S^T = K @ Q^T (C: col=li -> t, row -> s)
    f32x4 sacc[4];
#pragma unroll
    for (int mt = 0; mt < 4; ++mt) sacc[mt] = (f32x4){0.f, 0.f, 0.f, 0.f};
#pragma unroll
    for (int kk = 0; kk < 2; ++kk)
#pragma unroll
      for (int mt = 0; mt < 4; ++mt)
        sacc[mt] = __builtin_amdgcn_mfma_f32_16x16x32_bf16(kf[kk][mt], qf[kk], sacc[mt], 0, 0, 0);

    // P = f * exp2(S): read f (LDS b64 or global fallback), overwrite in place
    const int trow = w * 16 + li;   // this lane's t row in the block tile
#pragma unroll
    for (int mt = 0; mt < 4; ++mt) {
      // f chunk for s = mt*16+lq*4..: 16B-chunk index c = mt*2 + (lq>>1), slot swizzled
      const int cx = (mt * 2 + (lq >> 1)) ^ (trow & 7);
      u16* faddr = Fb + ((size_t)trow * 8 + cx) * 8 + (lq & 1) * 4;
      short4v fr;
      if (isf32) {
        const f32x4 fx = *(const f32x4*)&f32p[(size_t)(t0 + trow) * T_SEQ + s0 + mt * 16 + lq * 4];
        fr[0] = (short)f2bf(fx[0]); fr[1] = (short)f2bf(fx[1]);
        fr[2] = (short)f2bf(fx[2]); fr[3] = (short)f2bf(fx[3]);
      } else {
        fr = *(const short4v*)faddr;
      }
      u16 pk[4];
#pragma unroll
      for (int r = 0; r < 4; ++r) {
        const float e = __builtin_amdgcn_exp2f(sacc[mt][r]);
        const float p = b2f((u16)fr[r]) * e;
        den += p;
        pk[r] = f2bf(p);
      }
      *(short4v*)faddr = *(const short4v*)pk;   // in-place: wave-private row
    }

    // O += P @ V (A=P from Fl, B=V^T from Vl)
#pragma unroll
    for (int kk = 0; kk < 2; ++kk) {
      const int cxp = ((kk * 4 + lq) ^ (trow & 7));
      const short8 pf = *(const short8*)&Fb[((size_t)trow * 8 + cxp) * 8];
#pragma unroll
      for (int dn = 0; dn < 4; ++dn) {
        const int d = dn * 16 + li;
        const int cv = d * 8 + ((kk * 4 + lq) ^ (d & 7));
        const short8 vf = *(const short8*)&Vb[(size_t)cv * 8];
        oacc[dn] = __builtin_amdgcn_mfma_f32_16x16x32_bf16(pf, vf, oacc[dn], 0, 0, 0);
      }
    }
    __syncthreads();
  }

  // den: lanes {li, li+16, li+32, li+48} hold disjoint s-partials for t-col li
  den += __shfl_xor(den, 16, 64);
  den += __shfl_xor(den, 32, 64);

  // epilogue: scale + transpose via Kl scratch (wave-private 16x72 region)
  __syncthreads();   // all waves done reading K/V/F
  u16* pw = &Kl[0][0] + w * 1152;
#pragma unroll
  for (int r = 0; r < 4; ++r) {
    const float rd = 1.0f / __shfl(den, lq * 4 + r, 64);
#pragma unroll
    for (int dn = 0; dn < 4; ++dn)
      pw[(lq * 4 + r) * 72 + dn * 16 + li] = f2bf(oacc[dn][r] * rd);
  }
  // wave-private region: no barrier. 2 coalesced 16B stores per lane.
#pragma unroll
  for (int p = 0; p < 2; ++p) {
    const int idx = p * 64 + lane;
    const int rloc = idx >> 3, c = idx & 7;
    const short8 vv = *(const short8*)&pw[rloc * 72 + c * 8];
    *(short8*)&ao[(size_t)(b * T_SEQ + t0 + w * 16 + rloc) * DM + h * HD + c * 8] = vv;
  }
#undef STAGE_KV
}

// ---------------- output projection GEMM (fp32 output) ----------------
__global__ __launch_bounds__(256, 4) void oproj_kernel(
    const u16* __restrict__ A, const void* __restrict__ Wov,
    const float* __restrict__ bo, int isf32, float* __restrict__ out)
{
  __shared__ alignas(16) short lsA[4][128][8];
  __shared__ alignas(16) short lsB[4][128][8];

  const int tid = threadIdx.x;
  const int lane = tid & 63;
  const int wv = tid >> 6;
  const int lq = lane >> 4, li = lane & 15;
  const int wm = wv >> 1, wn = wv & 1;

  const int m0 = blockIdx.y * 128;
  const int n0 = blockIdx.x * 128;

  f32x4 acc[4][4];
#pragma unroll
  for (int i = 0; i < 4; i++)
#pragma unroll
    for (int j = 0; j < 4; j++) acc[i][j] = (f32x4){0.f, 0.f, 0.f, 0.f};

  for (int k0 = 0; k0 < DM; k0 += 32) {
#pragma unroll
    for (int r = 0; r < 2; ++r) {
      const int row = r * 64 + lane;
      gl_lds16(&A[(size_t)(m0 + row) * DM + k0 + wv * 8], &lsA[wv][row][0]);
    }
    if (isf32) {
      const float* W32 = (const float*)Wov;
#pragma unroll
      for (int r = 0; r < 2; ++r) {
        const int idx = tid + 256 * r;
        const int row = idx >> 2, slab = idx & 3;
        *(short8*)&lsB[slab][row][0] = cvt8(&W32[(size_t)(n0 + row) * DM + k0 + slab * 8]);
      }
    } else {
      const u16* W16 = (const u16*)Wov;
#pragma unroll
      for (int r = 0; r < 2; ++r) {
        const int row = r * 64 + lane;
        gl_lds16(&W16[(size_t)(n0 + row) * DM + k0 + wv * 8], &lsB[wv][row][0]);
      }
    }
    __syncthreads();
    short8 af[4], bf[4];
#pragma unroll
    for (int mt = 0; mt < 4; ++mt)
      af[mt] = *(const short8*)&lsA[lq][wm * 64 + mt * 16 + li][0];
#pragma unroll
    for (int nt = 0; nt < 4; ++nt)
      bf[nt] = *(const short8*)&lsB[lq][wn * 64 + nt * 16 + li][0];
#pragma unroll
    for (int mt = 0; mt < 4; ++mt)
#pragma unroll
      for (int nt = 0; nt < 4; ++nt)
        acc[mt][nt] = __builtin_amdgcn_mfma_f32_16x16x32_bf16(af[mt], bf[nt], acc[mt][nt], 0, 0, 0);
    __syncthreads();
  }

  float bs[4];
#pragma unroll
  for (int nt = 0; nt < 4; ++nt) bs[nt] = bo[n0 + wn * 64 + nt * 16 + li];

#pragma unroll
  for (int mt = 0; mt < 4; ++mt) {
    const int mbase = m0 + wm * 64 + mt * 16 + lq * 4;
#pragma unroll
    for (int nt = 0; nt < 4; ++nt) {
      const int n = n0 + wn * 64 + nt * 16 + li;
#pragma unroll
      for (int r = 0; r < 4; ++r)
        out[(size_t)(mbase + r) * DM + n] = acc[mt][nt][r] + bs[nt];
    }
  }
}

extern "C" void kernel_launch(void* const* d_in, const int* in_sizes, int n_in,
                              void* d_out, int out_size, void* d_ws, size_t ws_size,
                              hipStream_t stream) {
  (void)in_sizes; (void)n_in; (void)out_size;
  const float* hs = (const float*)d_in[0];
  const float* fa = (const float*)d_in[1];
  const float* Wq = (const float*)d_in[2];
  const float* bq = (const float*)d_in[3];
  const float* Wk = (const float*)d_in[4];
  const float* bk = (const float*)d_in[5];
  const float* Wv = (const float*)d_in[6];
  const float* bv = (const float*)d_in[7];
  const float* Wo = (const float*)d_in[8];
  const float* bo = (const float*)d_in[9];
  float* out = (float*)d_out;

  const size_t NEED = 256 + 2u * (8388608u + 4194304u + 4u * 1048576u + 4u * 4194304u);
  char* base = (char*)d_ws + 256;
  if (ws_size >= NEED) {
    u16* fb  = (u16*)base;
    u16* hsb = fb + 8388608u;
    u16* Wqb = hsb + 4194304u;
    u16* Wkb = Wqb + 1048576u;
    u16* Wvb = Wkb + 1048576u;
    u16* Wob = Wvb + 1048576u;
    u16* qw  = Wob + 1048576u;
    u16* kw  = qw + 4194304u;
    u16* vw  = kw + 4194304u;
    u16* aw  = vw + 4194304u;
    cvt_kernel<<<8192, 256, 0, stream>>>(hs, fa, Wq, Wk, Wv, Wo, hsb, fb, Wqb, Wkb, Wvb, Wob);
    qkv_kernel<<<dim3(8, 32, 3), 256, 0, stream>>>(hsb, Wqb, bq, Wkb, bk, Wvb, bv, 0, qw, kw, vw);
    attn_kernel<<<dim3(32, 16, 2), 256, 0, stream>>>(qw, kw, vw, fb, 0, aw);
    oproj_kernel<<<dim3(8, 32, 1), 256, 0, stream>>>(aw, Wob, bo, 0, out);
  } else {
    u16* qw = (u16*)base;
    u16* kw = qw + 4194304u;
    u16* vw = kw + 4194304u;
    u16* aw = vw + 4194304u;
    qkv_kernel<<<dim3(8, 32, 3), 256, 0, stream>>>(hs, Wq, bq, Wk, bk, Wv, bv, 1, qw, kw, vw);
    attn_kernel<<<dim3(32, 16, 2), 256, 0, stream>>>(qw, kw, vw, fa, 1, aw);
    oproj_kernel<<<dim3(8, 32, 1), 256, 0, stream>>>(aw, Wo, bo, 1, out);
  }
}